// Round 4
// baseline (3465.412 us; speedup 1.0000x reference)
//
#include <hip/hip_runtime.h>
#include <hip/hip_bf16.h>

#define RR 8
#define BB 32
#define CIN 21
#define CC 128
#define LL 4096
#define TT 64
#define GS 80   // LDS g-tile row stride (floats)

// -------------------- input projection: h0[b,o,t] = w0[o,:]@x[b,:,t] + b0[o]
__global__ void proj_kernel(const float* __restrict__ x, const float* __restrict__ w0,
                            const float* __restrict__ b0, float* __restrict__ h) {
    int idx = blockIdx.x * 256 + threadIdx.x;   // b*C*L + o*L + t
    int t = idx & (LL - 1);
    int o = (idx >> 12) & (CC - 1);
    int b = idx >> 19;
    const float* xb = x + (size_t)b * CIN * LL + t;
    const float* w = w0 + o * CIN;
    float acc = b0[o];
#pragma unroll
    for (int i = 0; i < CIN; i++) acc = fmaf(w[i], xb[i * LL], acc);
    h[idx] = acc;
}

// -------------------- weight transpose: [r][o][i](,kk) -> [r][i][o](,kk)
__global__ void transpose_kernel(const float* __restrict__ sw, const float* __restrict__ gw,
                                 const float* __restrict__ skw, const float* __restrict__ rew,
                                 float* __restrict__ swT, float* __restrict__ gwT,
                                 float* __restrict__ skwT, float* __restrict__ rewT) {
    int idx = blockIdx.x * 256 + threadIdx.x;   // over R*C*C = 131072
    int r = idx >> 14;
    int o = (idx >> 7) & (CC - 1);
    int i = idx & (CC - 1);
    int dst = (r * CC + i) * CC + o;
    skwT[dst] = skw[idx];
    rewT[dst] = rew[idx];
    ((float2*)swT)[dst] = ((const float2*)sw)[idx];   // {kk=0, kk=1} pair
    ((float2*)gwT)[dst] = ((const float2*)gw)[idx];
}

// -------------------- fused layer: signal/gate dilated convs + sigmoid gate + skip/res matmuls
__global__ void __launch_bounds__(256) layer_kernel(
    const float* __restrict__ hcur, float* __restrict__ hnext,
    float* __restrict__ skipbuf,
    const float* __restrict__ swT, const float* __restrict__ gwT,
    const float* __restrict__ skwT, const float* __restrict__ rewT,
    const float* __restrict__ csw, const float* __restrict__ cgw,
    const float* __restrict__ z,
    float* __restrict__ out,
    int off0, int first, int last) {
    __shared__ float smem[2 * CC * TT];          // 64 KB
    float* sHoff = smem;                         // [128][64]  h[b,k,t-off0]
    float* sHm1 = smem + CC * TT;                // [128][64]  h[b,k,t-1]

    int tid = threadIdx.x;
    int b = blockIdx.x >> 6;
    int t0 = (blockIdx.x & 63) * TT;

    const float* hb = hcur + (size_t)b * (CC * LL);
    // phase 0: stage shifted tiles (zero left pad)
    for (int m = 0; m < 32; m++) {
        int e = (m << 8) + tid;                  // e = k*64 + j
        int k = e >> 6, j = e & 63;
        int t1 = t0 - 1 + j;
        int t2 = t0 - off0 + j;
        sHm1[e] = (t1 >= 0) ? hb[k * LL + t1] : 0.f;
        sHoff[e] = (t2 >= 0) ? hb[k * LL + t2] : 0.f;
    }
    __syncthreads();

    int tx = tid & 7;    // 8 time-groups of 8
    int ty = tid >> 3;   // 32 o-groups of 4
    int tb = tx * 8;
    int ob = ty * 4;

    float sig[4][8], gat[4][8];
#pragma unroll
    for (int a = 0; a < 4; a++)
#pragma unroll
        for (int j = 0; j < 8; j++) { sig[a][j] = 0.f; gat[a][j] = 0.f; }

    const float4* Hoff4 = (const float4*)sHoff;
    const float4* Hm14 = (const float4*)sHm1;
    const float4* sw4 = (const float4*)swT;
    const float4* gw4 = (const float4*)gwT;

    // phase 1: signal/gate — 2-tap GEMM over input channels
    for (int k = 0; k < CC; k++) {
        float4 f0 = Hoff4[k * 16 + tx * 2];
        float4 f1 = Hoff4[k * 16 + tx * 2 + 1];
        float4 m0 = Hm14[k * 16 + tx * 2];
        float4 m1 = Hm14[k * 16 + tx * 2 + 1];
        float hof[8] = {f0.x, f0.y, f0.z, f0.w, f1.x, f1.y, f1.z, f1.w};
        float hm1[8] = {m0.x, m0.y, m0.z, m0.w, m1.x, m1.y, m1.z, m1.w};
        int wi = (k * CC + ob) >> 1;             // float4 index over {o,kk} pairs
        float4 ws0 = sw4[wi], ws1 = sw4[wi + 1];
        float4 wg0 = gw4[wi], wg1 = gw4[wi + 1];
#pragma unroll
        for (int j = 0; j < 8; j++) {
            sig[0][j] = fmaf(ws0.x, hof[j], fmaf(ws0.y, hm1[j], sig[0][j]));
            sig[1][j] = fmaf(ws0.z, hof[j], fmaf(ws0.w, hm1[j], sig[1][j]));
            sig[2][j] = fmaf(ws1.x, hof[j], fmaf(ws1.y, hm1[j], sig[2][j]));
            sig[3][j] = fmaf(ws1.z, hof[j], fmaf(ws1.w, hm1[j], sig[3][j]));
            gat[0][j] = fmaf(wg0.x, hof[j], fmaf(wg0.y, hm1[j], gat[0][j]));
            gat[1][j] = fmaf(wg0.z, hof[j], fmaf(wg0.w, hm1[j], gat[1][j]));
            gat[2][j] = fmaf(wg1.x, hof[j], fmaf(wg1.y, hm1[j], gat[2][j]));
            gat[3][j] = fmaf(wg1.z, hof[j], fmaf(wg1.w, hm1[j], gat[3][j]));
        }
    }

    // conditioning + gated activation
    const float* zb = z + b * LL + t0 + tb;
    float zv[8];
#pragma unroll
    for (int j = 0; j < 8; j++) zv[j] = zb[j];
    float g[4][8];
#pragma unroll
    for (int a = 0; a < 4; a++) {
        float cs = csw[ob + a], cg = cgw[ob + a];
#pragma unroll
        for (int j = 0; j < 8; j++) {
            float s = fmaf(cs, zv[j], sig[a][j]);
            float t = fmaf(cg, zv[j], gat[a][j]);
            g[a][j] = s / (1.f + __expf(-t));
        }
    }
    __syncthreads();
    // write g tile [128][GS]
#pragma unroll
    for (int a = 0; a < 4; a++) {
        float* row = smem + (ob + a) * GS + tb;
        ((float4*)row)[0] = make_float4(g[a][0], g[a][1], g[a][2], g[a][3]);
        ((float4*)row)[1] = make_float4(g[a][4], g[a][5], g[a][6], g[a][7]);
    }
    __syncthreads();

    // phase 2: skip/res GEMMs over g channels
    float sk[4][8], rs[4][8];
#pragma unroll
    for (int a = 0; a < 4; a++)
#pragma unroll
        for (int j = 0; j < 8; j++) { sk[a][j] = 0.f; rs[a][j] = 0.f; }

    const float4* G4 = (const float4*)smem;
    for (int k = 0; k < CC; k++) {
        int gi = (k * GS + tb) >> 2;
        float4 a0 = G4[gi], a1 = G4[gi + 1];
        float gv[8] = {a0.x, a0.y, a0.z, a0.w, a1.x, a1.y, a1.z, a1.w};
        float4 wk = *(const float4*)(skwT + k * CC + ob);
        float4 wr = *(const float4*)(rewT + k * CC + ob);
#pragma unroll
        for (int j = 0; j < 8; j++) {
            sk[0][j] = fmaf(wk.x, gv[j], sk[0][j]);
            sk[1][j] = fmaf(wk.y, gv[j], sk[1][j]);
            sk[2][j] = fmaf(wk.z, gv[j], sk[2][j]);
            sk[3][j] = fmaf(wk.w, gv[j], sk[3][j]);
            rs[0][j] = fmaf(wr.x, gv[j], rs[0][j]);
            rs[1][j] = fmaf(wr.y, gv[j], rs[1][j]);
            rs[2][j] = fmaf(wr.z, gv[j], rs[2][j]);
            rs[3][j] = fmaf(wr.w, gv[j], rs[3][j]);
        }
    }

    // epilogue: h_next = res + (first ? orig : g); skip accumulate; fp32 out on last layer
    const size_t NCL = (size_t)BB * CC * LL;
    size_t gbase = (size_t)b * (CC * LL) + t0 + tb;
#pragma unroll
    for (int a = 0; a < 4; a++) {
        size_t row = gbase + (size_t)(ob + a) * LL;
        float hv[8], sv[8];
#pragma unroll
        for (int j = 0; j < 8; j++) {
            hv[j] = rs[a][j] + (first ? hcur[row + j] : g[a][j]);
            sv[j] = sk[a][j] + (first ? 0.f : skipbuf[row + j]);
        }
        float* hdst = last ? (out + row) : (hnext + row);
        float* sdst = last ? (out + NCL + row) : (skipbuf + row);
        ((float4*)hdst)[0] = make_float4(hv[0], hv[1], hv[2], hv[3]);
        ((float4*)hdst)[1] = make_float4(hv[4], hv[5], hv[6], hv[7]);
        ((float4*)sdst)[0] = make_float4(sv[0], sv[1], sv[2], sv[3]);
        ((float4*)sdst)[1] = make_float4(sv[4], sv[5], sv[6], sv[7]);
    }
}

extern "C" void kernel_launch(void* const* d_in, const int* in_sizes, int n_in,
                              void* d_out, int out_size, void* d_ws, size_t ws_size,
                              hipStream_t stream) {
    const float* x = (const float*)d_in[0];
    const float* z = (const float*)d_in[1];
    const float* w0 = (const float*)d_in[2];
    const float* b0 = (const float*)d_in[3];
    const float* sw = (const float*)d_in[4];
    const float* gw = (const float*)d_in[5];
    const float* csw = (const float*)d_in[6];
    const float* cgw = (const float*)d_in[7];
    const float* rew = (const float*)d_in[8];
    const float* skw = (const float*)d_in[9];

    float* ws = (float*)d_ws;
    const size_t NCL = (size_t)BB * CC * LL;
    float* hA = ws;
    float* hB = hA + NCL;
    float* skipb = hB + NCL;
    float* swT = skipb + NCL;
    float* gwT = swT + (size_t)RR * CC * CC * 2;
    float* skwT = gwT + (size_t)RR * CC * CC * 2;
    float* rewT = skwT + (size_t)RR * CC * CC;

    transpose_kernel<<<RR * CC * CC / 256, 256, 0, stream>>>(sw, gw, skw, rew, swT, gwT, skwT, rewT);
    proj_kernel<<<NCL / 256, 256, 0, stream>>>(x, w0, b0, hA);

    float* hc = hA;
    float* hn = hB;
    for (int ii = 0; ii < RR; ii++) {
        int d = 1 << ii;
        int off0 = d + 1;   // taps: t-(d+1) (kk=0) and t-1 (kk=1); holds for ii==0 (pad=K=2)
        layer_kernel<<<BB * (LL / TT), 256, 0, stream>>>(
            hc, hn, skipb,
            swT + (size_t)ii * CC * CC * 2, gwT + (size_t)ii * CC * CC * 2,
            skwT + (size_t)ii * CC * CC, rewT + (size_t)ii * CC * CC,
            csw + ii * CC, cgw + ii * CC, z,
            (float*)d_out, off0, ii == 0 ? 1 : 0, ii == RR - 1 ? 1 : 0);
        float* tmp = hc; hc = hn; hn = tmp;
    }
}

// Round 6
// 1992.027 us; speedup vs baseline: 1.7396x; 1.7396x over previous
//
#include <hip/hip_runtime.h>
#include <hip/hip_bf16.h>

#define RR 8
#define BB 32
#define CIN 21
#define CC 128
#define LL 4096
#define TT 32    // time-tile
#define HP 264   // sH row stride (shorts): 256 + 8 pad, 16B-aligned rows
#define GP 136   // sG row stride (shorts): 128 + 8 pad

typedef short s16x8 __attribute__((ext_vector_type(8)));
typedef float f32x4 __attribute__((ext_vector_type(4)));

__device__ __forceinline__ unsigned short f2b(float f) {
    __hip_bfloat16 h = __float2bfloat16(f);
    return *reinterpret_cast<unsigned short*>(&h);
}
__device__ __forceinline__ float b2f(unsigned short u) {
    __hip_bfloat16 h;
    *reinterpret_cast<unsigned short*>(&h) = u;
    return __bfloat162float(h);
}

// ---- pack weights to split-bf16 (hi/lo) MFMA rows.
// Wsg[r][o][k]: o<128 signal, o>=128 gate; k<128 tap0 (t-off0), k>=128 tap1 (t-1).
// Wkr[r][o2][c]: o2<128 skip, o2>=128 res.
__global__ void prep_kernel(const float* __restrict__ sw, const float* __restrict__ gw,
                            const float* __restrict__ skw, const float* __restrict__ rew,
                            unsigned short* __restrict__ WsgH, unsigned short* __restrict__ WsgL,
                            unsigned short* __restrict__ WkrH, unsigned short* __restrict__ WkrL) {
    int idx = blockIdx.x * 256 + threadIdx.x;        // over R*256*256 = 524288
    int r = idx >> 16;
    int rem = idx & 65535;
    int o = rem >> 8;
    int k = rem & 255;
    int c = k & 127;
    int tap = k >> 7;
    float v = (o < 128) ? sw[(((r * 128 + o) * 128 + c) << 1) + tap]
                        : gw[(((r * 128 + (o - 128)) * 128 + c) << 1) + tap];
    unsigned short hi = f2b(v);
    WsgH[idx] = hi;
    WsgL[idx] = f2b(v - b2f(hi));
    if (idx < RR * 256 * 128) {
        int r2 = idx >> 15;
        int rem2 = idx & 32767;
        int o2 = rem2 >> 7;
        int c2 = rem2 & 127;
        float v2 = (o2 < 128) ? skw[(r2 * 128 + o2) * 128 + c2]
                              : rew[(r2 * 128 + (o2 - 128)) * 128 + c2];
        unsigned short hi2 = f2b(v2);
        WkrH[idx] = hi2;
        WkrL[idx] = f2b(v2 - b2f(hi2));
    }
}

// ---- input projection: h0 fp32 [b][t][c]
__global__ void proj_kernel(const float* __restrict__ x, const float* __restrict__ w0,
                            const float* __restrict__ b0, float* __restrict__ h0) {
    int idx = blockIdx.x * 256 + threadIdx.x;        // ((b*L)+t)*C + c
    int c = idx & 127;
    int t = (idx >> 7) & (LL - 1);
    int b = idx >> 19;
    const float* xb = x + (size_t)b * CIN * LL + t;
    const float* w = w0 + c * CIN;
    float acc = b0[c];
#pragma unroll
    for (int i = 0; i < CIN; i++) acc = fmaf(w[i], xb[i * LL], acc);
    h0[idx] = acc;
}

// ---- fused split-bf16 MFMA layer
__global__ void __launch_bounds__(256) layer_kernel(
    const float* __restrict__ hcur,            // f32 [B][L][C]
    float* __restrict__ hnext,                 // f32 [B][L][C]
    float* __restrict__ skipbuf,               // f32 [B][L][C]
    const unsigned short* __restrict__ WsgH, const unsigned short* __restrict__ WsgL,
    const unsigned short* __restrict__ WkrH, const unsigned short* __restrict__ WkrL,
    const float* __restrict__ csw, const float* __restrict__ cgw,
    const float* __restrict__ z,
    float* __restrict__ out,                   // f32 [2][B][C][L] on last layer
    int off0, int first, int last) {
    __shared__ unsigned short sHhi[TT * HP];   // Hcat^T hi [t][k], k = win*128+ch
    __shared__ unsigned short sHlo[TT * HP];
    __shared__ unsigned short sGhi[TT * GP];   // g^T hi [t][c]
    __shared__ unsigned short sGlo[TT * GP];

    int tid = threadIdx.x;
    int b = blockIdx.x >> 7;                   // 32 batches
    int t0 = (blockIdx.x & 127) * TT;          // 128 t-tiles

    // ---- phase 0: stage shifted H windows, transposed, split to hi/lo bf16
    {
        int win = tid >> 7;                    // 0: t-off0, 1: t-1
        int tid7 = tid & 127;
        int col4 = tid7 & 31;                  // float4 column (4 ch)
        int r0 = tid7 >> 5;                    // 0..3
        int shift = win ? 1 : off0;
        const float* hb = hcur + (size_t)b * LL * CC;
#pragma unroll
        for (int it = 0; it < 8; it++) {
            int r = r0 + 4 * it;               // 0..31
            int tsrc = t0 + r - shift;
            float4 v = make_float4(0.f, 0.f, 0.f, 0.f);
            if (tsrc >= 0) v = *(const float4*)(hb + (size_t)tsrc * CC + col4 * 4);
            unsigned short h0 = f2b(v.x), h1 = f2b(v.y), h2 = f2b(v.z), h3 = f2b(v.w);
            ushort4 hv = make_ushort4(h0, h1, h2, h3);
            ushort4 lv = make_ushort4(f2b(v.x - b2f(h0)), f2b(v.y - b2f(h1)),
                                      f2b(v.z - b2f(h2)), f2b(v.w - b2f(h3)));
            int off = r * HP + win * 128 + col4 * 4;
            *(ushort4*)(sHhi + off) = hv;
            *(ushort4*)(sHlo + off) = lv;
        }
    }
    __syncthreads();

    int wave = tid >> 6;
    int lane = tid & 63;
    int l15 = lane & 15;
    int quad = lane >> 4;

    // ---- GEMM1: [sig;gate]^T[t][o], M=32, N=256, K=256, split-bf16 3-pass
    f32x4 acc1[2][4];
#pragma unroll
    for (int m = 0; m < 2; m++)
#pragma unroll
        for (int n = 0; n < 4; n++) acc1[m][n] = (f32x4){0.f, 0.f, 0.f, 0.f};

    for (int kk = 0; kk < 8; kk++) {
        s16x8 Ah[2], Al[2], Bh[4], Bl[4];
#pragma unroll
        for (int m = 0; m < 2; m++) {
            int off = (m * 16 + l15) * HP + kk * 32 + quad * 8;
            Ah[m] = *(const s16x8*)(sHhi + off);
            Al[m] = *(const s16x8*)(sHlo + off);
        }
#pragma unroll
        for (int n = 0; n < 4; n++) {
            int o = (wave + 4 * n) * 16 + l15;
            Bh[n] = *(const s16x8*)(WsgH + o * 256 + kk * 32 + quad * 8);
            Bl[n] = *(const s16x8*)(WsgL + o * 256 + kk * 32 + quad * 8);
        }
#pragma unroll
        for (int m = 0; m < 2; m++)
#pragma unroll
            for (int n = 0; n < 4; n++) {
                acc1[m][n] = __builtin_amdgcn_mfma_f32_16x16x32_bf16(Ah[m], Bh[n], acc1[m][n], 0, 0, 0);
                acc1[m][n] = __builtin_amdgcn_mfma_f32_16x16x32_bf16(Al[m], Bh[n], acc1[m][n], 0, 0, 0);
                acc1[m][n] = __builtin_amdgcn_mfma_f32_16x16x32_bf16(Ah[m], Bl[n], acc1[m][n], 0, 0, 0);
            }
    }

    // ---- conditioning + gated activation (fp32, in-register)
    const float* zb = z + (size_t)b * LL + t0;
    float cs0 = csw[wave * 16 + l15], cs1 = csw[64 + wave * 16 + l15];
    float cg0 = cgw[wave * 16 + l15], cg1 = cgw[64 + wave * 16 + l15];
    float g[2][2][4];
#pragma unroll
    for (int m = 0; m < 2; m++) {
#pragma unroll
        for (int reg = 0; reg < 4; reg++) {
            float zv = zb[m * 16 + quad * 4 + reg];
#pragma unroll
            for (int p = 0; p < 2; p++) {
                float cs = p ? cs1 : cs0;
                float cg = p ? cg1 : cg0;
                float s = fmaf(cs, zv, acc1[m][p][reg]);
                float t = fmaf(cg, zv, acc1[m][p + 2][reg]);
                g[m][p][reg] = s / (1.f + __expf(-t));
            }
        }
    }
    // write g^T [t][c] split hi/lo to LDS for GEMM2 A-operand
#pragma unroll
    for (int m = 0; m < 2; m++)
#pragma unroll
        for (int p = 0; p < 2; p++) {
            int c = wave * 16 + p * 64 + l15;
#pragma unroll
            for (int reg = 0; reg < 4; reg++) {
                int t = m * 16 + quad * 4 + reg;
                float v = g[m][p][reg];
                unsigned short hi = f2b(v);
                sGhi[t * GP + c] = hi;
                sGlo[t * GP + c] = f2b(v - b2f(hi));
            }
        }
    __syncthreads();

    // ---- GEMM2: [skip;res]^T[t][o2], K=128, split-bf16 3-pass
    f32x4 acc2[2][4];
#pragma unroll
    for (int m = 0; m < 2; m++)
#pragma unroll
        for (int n = 0; n < 4; n++) acc2[m][n] = (f32x4){0.f, 0.f, 0.f, 0.f};

    for (int kk = 0; kk < 4; kk++) {
        s16x8 Ah[2], Al[2], Bh[4], Bl[4];
#pragma unroll
        for (int m = 0; m < 2; m++) {
            int off = (m * 16 + l15) * GP + kk * 32 + quad * 8;
            Ah[m] = *(const s16x8*)(sGhi + off);
            Al[m] = *(const s16x8*)(sGlo + off);
        }
#pragma unroll
        for (int n = 0; n < 4; n++) {
            int o2 = (wave + 4 * n) * 16 + l15;
            Bh[n] = *(const s16x8*)(WkrH + o2 * 128 + kk * 32 + quad * 8);
            Bl[n] = *(const s16x8*)(WkrL + o2 * 128 + kk * 32 + quad * 8);
        }
#pragma unroll
        for (int m = 0; m < 2; m++)
#pragma unroll
            for (int n = 0; n < 4; n++) {
                acc2[m][n] = __builtin_amdgcn_mfma_f32_16x16x32_bf16(Ah[m], Bh[n], acc2[m][n], 0, 0, 0);
                acc2[m][n] = __builtin_amdgcn_mfma_f32_16x16x32_bf16(Al[m], Bh[n], acc2[m][n], 0, 0, 0);
                acc2[m][n] = __builtin_amdgcn_mfma_f32_16x16x32_bf16(Ah[m], Bl[n], acc2[m][n], 0, 0, 0);
            }
    }

    // ---- epilogue: h_next = res + (first ? orig : g); skip accumulate
    #pragma unroll
    for (int m = 0; m < 2; m++)
#pragma unroll
        for (int p = 0; p < 2; p++) {
            int c = wave * 16 + p * 64 + l15;
#pragma unroll
            for (int reg = 0; reg < 4; reg++) {
                int t = t0 + m * 16 + quad * 4 + reg;
                size_t idx = ((size_t)b * LL + t) * CC + c;
                float res = acc2[m][2 + p][reg];
                float skp = acc2[m][p][reg];
                float hv, sv;
                if (first) { hv = res + hcur[idx]; sv = skp; }
                else       { hv = res + g[m][p][reg]; sv = skp + skipbuf[idx]; }
                if (last) {
                    size_t oidx = ((size_t)b * CC + c) * LL + t;
                    out[oidx] = hv;
                    out[(size_t)BB * CC * LL + oidx] = sv;
                } else {
                    hnext[idx] = hv;
                    skipbuf[idx] = sv;
                }
            }
        }
}

extern "C" void kernel_launch(void* const* d_in, const int* in_sizes, int n_in,
                              void* d_out, int out_size, void* d_ws, size_t ws_size,
                              hipStream_t stream) {
    const float* x = (const float*)d_in[0];
    const float* z = (const float*)d_in[1];
    const float* w0 = (const float*)d_in[2];
    const float* b0 = (const float*)d_in[3];
    const float* sw = (const float*)d_in[4];
    const float* gw = (const float*)d_in[5];
    const float* csw = (const float*)d_in[6];
    const float* cgw = (const float*)d_in[7];
    const float* rew = (const float*)d_in[8];
    const float* skw = (const float*)d_in[9];

    const size_t NCL = (size_t)BB * CC * LL;           // 16,777,216
    float* hA = (float*)d_ws;
    float* hB = hA + NCL;
    float* skipb = hB + NCL;
    unsigned short* WsgH = (unsigned short*)(skipb + NCL);
    unsigned short* WsgL = WsgH + (size_t)RR * 256 * 256;
    unsigned short* WkrH = WsgL + (size_t)RR * 256 * 256;
    unsigned short* WkrL = WkrH + (size_t)RR * 256 * 128;

    prep_kernel<<<RR * 256 * 256 / 256, 256, 0, stream>>>(sw, gw, skw, rew, WsgH, WsgL, WkrH, WkrL);
    proj_kernel<<<NCL / 256, 256, 0, stream>>>(x, w0, b0, hA);

    float* hc = hA;
    float* hn = hB;
    for (int ii = 0; ii < RR; ii++) {
        int d = 1 << ii;
        int off0 = d + 1;   // taps: t-(d+1) (tap0) and t-1 (tap1); holds for ii==0 (pad=K=2)
        layer_kernel<<<BB * (LL / TT), 256, 0, stream>>>(
            hc, hn, skipb,
            WsgH + (size_t)ii * 256 * 256, WsgL + (size_t)ii * 256 * 256,
            WkrH + (size_t)ii * 256 * 128, WkrL + (size_t)ii * 256 * 128,
            csw + ii * CC, cgw + ii * CC, z,
            (float*)d_out, off0, ii == 0 ? 1 : 0, ii == RR - 1 ? 1 : 0);
        float* tmp = hc; hc = hn; hn = tmp;
    }
}